// Round 4
// baseline (1327.045 us; speedup 1.0000x reference)
//
#include <hip/hip_runtime.h>
#include <hip/hip_bf16.h>
#include <stdint.h>

// GCNDecoder one-buffer plan (ws >= ~257MB):
//  P1: gather->G4 -> stats4 (no store)
//  P3: gather->G4 -> h=act4 -> store h (buf)
//  P4: h->G1 -> stats1 (no store)
//  P6: h->G1 -> out1=act1+h -> store out1 over buf (in place) + dot(out1,wf)->out
//  P7: out1->G2 -> stats2 (no store)
//  P9: out1->G2 -> dot(act2,wf)->out
// out = bf + out1.wf + act2(Y2).wf  (atomic accumulation, k_zero seeds bf).
// Tiny-ws fallback: fully-chained recompute kernels (Tier C, known-correct).

typedef __attribute__((ext_vector_type(8))) short short8;
typedef __attribute__((ext_vector_type(4))) float f32x4;

__device__ __forceinline__ unsigned short bf16b(float f) {
  unsigned int u = __float_as_uint(f);
  return (unsigned short)((u + 0x7fffu + ((u >> 16) & 1u)) >> 16);  // RNE
}
__device__ __forceinline__ unsigned int packbf(float lo, float hi) {
  return (unsigned int)bf16b(lo) | ((unsigned int)bf16b(hi) << 16);
}
__device__ __forceinline__ float bflo(unsigned int u) { return __uint_as_float(u << 16); }
__device__ __forceinline__ float bfhi(unsigned int u) { return __uint_as_float(u & 0xffff0000u); }
__device__ __forceinline__ float bfs(short s) { return __uint_as_float(((unsigned int)(unsigned short)s) << 16); }
__device__ __forceinline__ float relu_(float x) { return fmaxf(x, 0.0f); }

// ---------------- tiny kernels ----------------
__global__ __launch_bounds__(256) void k_init(const int* __restrict__ ei,
                                              float* __restrict__ stats, int* __restrict__ flag) {
  const int t = threadIdx.x;
#pragma unroll
  for (int i = 0; i < 6; ++i) stats[t + 256 * i] = 0.f;
  if (t == 0) {
    int o = 0;
#pragma unroll
    for (int i = 0; i < 32; ++i) o |= ei[2 * i + 1];
    *flag = (o == 0) ? 1 : 0;  // 1 => int64 pairs, 0 => int32
  }
}

__global__ __launch_bounds__(256) void k_zero(float* __restrict__ out, const float* __restrict__ bfp, int E) {
  const int i = blockIdx.x * 256 + threadIdx.x;
  if (i < E) out[i] = bfp[0];
}

__global__ __launch_bounds__(256) void k_prep(
    const float* __restrict__ W4, const float* __restrict__ W1, const float* __restrict__ W2,
    unsigned short* __restrict__ wt4, unsigned short* __restrict__ wt1, unsigned short* __restrict__ wt2)
{
  const int b = blockIdx.x;           // 0..191
  const int t = threadIdx.x;
  const int wi = b >> 6;
  const int r = b & 63;
  const float* W = (wi == 0) ? W4 : (wi == 1) ? W1 : W2;
  unsigned short* Wt = (wi == 0) ? wt4 : (wi == 1) ? wt1 : wt2;
  const int flat = r * 1024 + t * 4;  // Wt[n][k] = W[k][n]
  const int n = flat >> 8;
  const int k = flat & 255;
  ushort4 o;
  o.x = bf16b(W[(k + 0) * 256 + n]);
  o.y = bf16b(W[(k + 1) * 256 + n]);
  o.z = bf16b(W[(k + 2) * 256 + n]);
  o.w = bf16b(W[(k + 3) * 256 + n]);
  *(ushort4*)(Wt + flat) = o;
}

// stats -> scale[c]=a, scale[256+c]=c_std, scale[512+c]=c_b (bias folded)
__global__ __launch_bounds__(256) void k_stats(
    const float* __restrict__ stats, const float* __restrict__ g, const float* __restrict__ be,
    const float* __restrict__ bias, float* __restrict__ scale, float invE)
{
  const int c = threadIdx.x;
  const float mean = stats[c] * invE;
  const float var = stats[256 + c] * invE - mean * mean;
  const float a = g[c] * rsqrtf(var + 1e-5f);
  const float cstd = be[c] - mean * a;
  scale[c] = a;
  scale[256 + c] = cstd;
  scale[512 + c] = fmaf(a, bias[c], cstd);
}

// ---------------- stats-only epilogue (bias added, E-guarded) ----------------
__device__ __forceinline__ void dev_epilogue_stats(f32x4 acc[4][4], const float* __restrict__ bias,
    float* __restrict__ stats, int m0, int E, int t)
{
  const int l = t & 63;
  const int wv = t >> 6;
  const int wr = wv >> 2;
  const int wc = wv & 3;
  const int colb = wc * 64 + (l & 15);
  float bj[4];
#pragma unroll
  for (int j = 0; j < 4; ++j) bj[j] = bias[colb + j * 16];

  float ssum[4] = {0.f, 0.f, 0.f, 0.f};
  float ssq[4] = {0.f, 0.f, 0.f, 0.f};
  const int rbase = m0 + wr * 64 + ((l >> 4) << 2);

#pragma unroll
  for (int i = 0; i < 4; ++i) {
#pragma unroll
    for (int j = 0; j < 4; ++j) {
      float v0 = acc[i][j][0] + bj[j];
      float v1 = acc[i][j][1] + bj[j];
      float v2 = acc[i][j][2] + bj[j];
      float v3 = acc[i][j][3] + bj[j];
      const int r0 = rbase + i * 16;
      if (r0 + 0 < E) { ssum[j] += v0; ssq[j] = fmaf(v0, v0, ssq[j]); }
      if (r0 + 1 < E) { ssum[j] += v1; ssq[j] = fmaf(v1, v1, ssq[j]); }
      if (r0 + 2 < E) { ssum[j] += v2; ssq[j] = fmaf(v2, v2, ssq[j]); }
      if (r0 + 3 < E) { ssum[j] += v3; ssq[j] = fmaf(v3, v3, ssq[j]); }
    }
  }
#pragma unroll
  for (int j = 0; j < 4; ++j) {
    ssum[j] += __shfl_xor(ssum[j], 16); ssum[j] += __shfl_xor(ssum[j], 32);
    ssq[j]  += __shfl_xor(ssq[j], 16);  ssq[j]  += __shfl_xor(ssq[j], 32);
  }
  const int g = l >> 4;
  float sg = (g == 0) ? ssum[0] : (g == 1) ? ssum[1] : (g == 2) ? ssum[2] : ssum[3];
  float qg = (g == 0) ? ssq[0] : (g == 1) ? ssq[1] : (g == 2) ? ssq[2] : ssq[3];
  const int col = wc * 64 + g * 16 + (l & 15);
  atomicAdd(&stats[col], sg);
  atomicAdd(&stats[256 + col], qg);
}

// ---------------- main GEMM pass: [128x256] tile, K=256 in 4x64, 8 waves ----------------
// APROC: 0 = gather x via edge_index (fp32->bf16), 1 = plain bf16 rows from Av
// EPI:   0 = stats only (bias)            1 = act -> store bf16 (Yout)
//        2 = act + resid(Yout) -> store in place + dot(wf)->out
//        3 = act dot(wf) -> out (no store)
template<int APROC, int EPI>
__global__ __launch_bounds__(512) void k_gemm2(
    const void* Av, const int* __restrict__ ei, const int* __restrict__ flagp,
    const unsigned short* __restrict__ Wt, const float* __restrict__ bias,
    const float* __restrict__ sc, const float* __restrict__ wf,
    unsigned short* Yout, float* __restrict__ stats, float* __restrict__ out, int E)
{
  __shared__ __align__(16) char aT[16384];
  __shared__ __align__(16) char bT[32768];
  __shared__ float sS[768];

  const int t = threadIdx.x;
  const int m0 = blockIdx.x * 128;

  if (EPI >= 1 && t < 256) {
    sS[t] = sc[t];
    sS[256 + t] = sc[512 + t];         // c_b (bias folded)
    if (EPI >= 2) sS[512 + t] = wf[t];
  }

  const int arow = t & 127;
  const int acg = t >> 7;
  const int brow = t & 255;
  const int bh = t >> 8;

  int sN = 0, dN = 0;
  if (APROC == 0) {
    int e = m0 + arow; if (e >= E) e = E - 1;
    if (flagp[0]) { sN = ei[2 * e]; dN = ei[2 * (E + e)]; }
    else          { sN = ei[e];     dN = ei[E + e]; }
  }

  f32x4 acc[4][4];
  f32x4 zz = {0.f, 0.f, 0.f, 0.f};
#pragma unroll
  for (int i = 0; i < 4; ++i)
#pragma unroll
    for (int j = 0; j < 4; ++j) acc[i][j] = zz;

  const int l = t & 63;
  const int wv = t >> 6;
  const int wr = wv >> 2;
  const int wc = wv & 3;
  const int sw = (l & 7) << 4;

  for (int ks = 0; ks < 4; ++ks) {
    if (ks) __syncthreads();
    // ---- stage A ----
    {
      const int kc0 = acg * 2;
      char* ap = aT + arow * 128;
      const int swa = (arow & 7) << 4;
      uint4 v0, v1;
      if (APROC == 0) {
        const float* xf = (const float*)Av;
        const int node = (ks < 2) ? sN : dN;
        const float* src = xf + node * 128 + (ks & 1) * 64 + kc0 * 8;
        float4 f0 = *(const float4*)(src);
        float4 f1 = *(const float4*)(src + 4);
        float4 f2 = *(const float4*)(src + 8);
        float4 f3 = *(const float4*)(src + 12);
        v0.x = packbf(f0.x, f0.y); v0.y = packbf(f0.z, f0.w);
        v0.z = packbf(f1.x, f1.y); v0.w = packbf(f1.z, f1.w);
        v1.x = packbf(f2.x, f2.y); v1.y = packbf(f2.z, f2.w);
        v1.z = packbf(f3.x, f3.y); v1.w = packbf(f3.z, f3.w);
      } else {
        const unsigned short* Ys = (const unsigned short*)Av;
        const size_t rb = (size_t)(m0 + arow) * 256 + ks * 64 + kc0 * 8;
        v0 = *(const uint4*)(Ys + rb);
        v1 = *(const uint4*)(Ys + rb + 8);
      }
      *(uint4*)(ap + ((kc0 * 16) ^ swa)) = v0;
      *(uint4*)(ap + (((kc0 + 1) * 16) ^ swa)) = v1;
    }
    // ---- stage B ----
    {
      const unsigned short* src = Wt + brow * 256 + ks * 64 + bh * 32;
      uint4 b0 = *(const uint4*)(src);
      uint4 b1 = *(const uint4*)(src + 8);
      uint4 b2 = *(const uint4*)(src + 16);
      uint4 b3 = *(const uint4*)(src + 24);
      char* bp = bT + brow * 128;
      const int swb = (brow & 7) << 4;
      const int kcb = bh * 4;
      *(uint4*)(bp + (((kcb + 0) * 16) ^ swb)) = b0;
      *(uint4*)(bp + (((kcb + 1) * 16) ^ swb)) = b1;
      *(uint4*)(bp + (((kcb + 2) * 16) ^ swb)) = b2;
      *(uint4*)(bp + (((kcb + 3) * 16) ^ swb)) = b3;
    }
    __syncthreads();
    // ---- compute ----
    {
      const int ar = wr * 64 + (l & 15);
      const int bn = wc * 64 + (l & 15);
#pragma unroll
      for (int kk = 0; kk < 2; ++kk) {
        const int koff = kk * 64 + ((l >> 4) << 4);
        short8 af[4], bfr[4];
#pragma unroll
        for (int i = 0; i < 4; ++i)
          af[i] = *(const short8*)(aT + (ar + i * 16) * 128 + (koff ^ sw));
#pragma unroll
        for (int j = 0; j < 4; ++j)
          bfr[j] = *(const short8*)(bT + (bn + j * 16) * 128 + (koff ^ sw));
#pragma unroll
        for (int i = 0; i < 4; ++i)
#pragma unroll
          for (int j = 0; j < 4; ++j)
            acc[i][j] = __builtin_amdgcn_mfma_f32_16x16x32_bf16(af[i], bfr[j], acc[i][j], 0, 0, 0);
      }
    }
  }

  if (EPI == 0) { dev_epilogue_stats(acc, bias, stats, m0, E, t); return; }

  // ---- act epilogue ----
  const int colb = wc * 64 + (l & 15);
  const int rbase = m0 + wr * 64 + ((l >> 4) << 2);
  const int odd = l & 1;
#pragma unroll
  for (int i = 0; i < 4; ++i) {
    const int r0 = rbase + i * 16;
    float dq0 = 0.f, dq1 = 0.f, dq2 = 0.f, dq3 = 0.f;
#pragma unroll
    for (int j = 0; j < 4; ++j) {
      const int col = colb + j * 16;
      const float a = sS[col], cb = sS[256 + col];
      float v0 = relu_(fmaf(acc[i][j][0], a, cb));
      float v1 = relu_(fmaf(acc[i][j][1], a, cb));
      float v2 = relu_(fmaf(acc[i][j][2], a, cb));
      float v3 = relu_(fmaf(acc[i][j][3], a, cb));
      if (EPI == 2) {  // residual h (L2-hot: same rows just staged)
        v0 += bfs(*(const short*)(Yout + (size_t)(r0 + 0) * 256 + col));
        v1 += bfs(*(const short*)(Yout + (size_t)(r0 + 1) * 256 + col));
        v2 += bfs(*(const short*)(Yout + (size_t)(r0 + 2) * 256 + col));
        v3 += bfs(*(const short*)(Yout + (size_t)(r0 + 3) * 256 + col));
      }
      if (EPI >= 2) {
        const float w = sS[512 + col];
        dq0 = fmaf(v0, w, dq0); dq1 = fmaf(v1, w, dq1);
        dq2 = fmaf(v2, w, dq2); dq3 = fmaf(v3, w, dq3);
      }
      if (EPI != 3) {  // pack row-pairs via shfl, store 2 cols at once
        float p0 = __shfl_xor(v0, 1), p1 = __shfl_xor(v1, 1);
        float p2 = __shfl_xor(v2, 1), p3 = __shfl_xor(v3, 1);
        float loA = odd ? p2 : v0, hiA = odd ? v2 : p0;
        float loB = odd ? p3 : v1, hiB = odd ? v3 : p1;
        const int ra = r0 + (odd ? 2 : 0);
        const int cp = col & ~1;
        *(unsigned int*)(Yout + (size_t)(ra + 0) * 256 + cp) = packbf(loA, hiA);
        *(unsigned int*)(Yout + (size_t)(ra + 1) * 256 + cp) = packbf(loB, hiB);
      }
    }
    if (EPI >= 2) {
      dq0 += __shfl_xor(dq0, 1); dq0 += __shfl_xor(dq0, 2); dq0 += __shfl_xor(dq0, 4); dq0 += __shfl_xor(dq0, 8);
      dq1 += __shfl_xor(dq1, 1); dq1 += __shfl_xor(dq1, 2); dq1 += __shfl_xor(dq1, 4); dq1 += __shfl_xor(dq1, 8);
      dq2 += __shfl_xor(dq2, 1); dq2 += __shfl_xor(dq2, 2); dq2 += __shfl_xor(dq2, 4); dq2 += __shfl_xor(dq2, 8);
      dq3 += __shfl_xor(dq3, 1); dq3 += __shfl_xor(dq3, 2); dq3 += __shfl_xor(dq3, 4); dq3 += __shfl_xor(dq3, 8);
      if ((l & 15) == 0) {
        if (r0 + 0 < E) atomicAdd(&out[r0 + 0], dq0);
        if (r0 + 1 < E) atomicAdd(&out[r0 + 1], dq1);
        if (r0 + 2 < E) atomicAdd(&out[r0 + 2], dq2);
        if (r0 + 3 < E) atomicAdd(&out[r0 + 3], dq3);
      }
    }
  }
}

// ---------------- Tier C fallback: fully-chained recompute (known-correct) ----------------
__device__ __forceinline__ void dev_stage_gather(char* hA, const float* __restrict__ x,
                                                 int sN, int dN, int t)
{
  const int row = t & 127;
  const int cg = t >> 7;
  const int node = (cg < 2) ? sN : dN;
  const float* src = x + node * 128 + (cg & 1) * 64;
  const int swr = (row & 7) << 4;
  char* hp = hA + row * 512;
#pragma unroll
  for (int u = 0; u < 8; ++u) {
    float4 f0 = *(const float4*)(src + u * 8);
    float4 f1 = *(const float4*)(src + u * 8 + 4);
    uint4 v;
    v.x = packbf(f0.x, f0.y); v.y = packbf(f0.z, f0.w);
    v.z = packbf(f1.x, f1.y); v.w = packbf(f1.z, f1.w);
    *(uint4*)(hp + ((cg * 128 + u * 16) ^ swr)) = v;
  }
}

__device__ __forceinline__ void dev_gemm_hA(f32x4 acc[4][4], const char* hA, char* bT,
                                            const unsigned short* __restrict__ Wt, int t)
{
  const int l = t & 63, wv = t >> 6, wr = wv >> 2, wc = wv & 3;
  const int sw = (l & 7) << 4;
  const int brow = t & 255, bh = t >> 8;
  f32x4 zz = {0.f, 0.f, 0.f, 0.f};
#pragma unroll
  for (int i = 0; i < 4; ++i)
#pragma unroll
    for (int j = 0; j < 4; ++j) acc[i][j] = zz;

  for (int ks = 0; ks < 4; ++ks) {
    const unsigned short* srcb = Wt + brow * 256 + ks * 64 + bh * 32;
    uint4 b0 = *(const uint4*)(srcb);
    uint4 b1 = *(const uint4*)(srcb + 8);
    uint4 b2 = *(const uint4*)(srcb + 16);
    uint4 b3 = *(const uint4*)(srcb + 24);
    __syncthreads();
    char* bp = bT + brow * 128;
    const int swb = (brow & 7) << 4;
    const int kcb = bh * 4;
    *(uint4*)(bp + (((kcb + 0) * 16) ^ swb)) = b0;
    *(uint4*)(bp + (((kcb + 1) * 16) ^ swb)) = b1;
    *(uint4*)(bp + (((kcb + 2) * 16) ^ swb)) = b2;
    *(uint4*)(bp + (((kcb + 3) * 16) ^ swb)) = b3;
    __syncthreads();
    const int ar = wr * 64 + (l & 15);
    const int bn = wc * 64 + (l & 15);
#pragma unroll
    for (int kk = 0; kk < 2; ++kk) {
      const int kbA = ks * 128 + kk * 64 + ((l >> 4) << 4);
      const int kbB = kk * 64 + ((l >> 4) << 4);
      short8 af[4], bfr[4];
#pragma unroll
      for (int i = 0; i < 4; ++i)
        af[i] = *(const short8*)(hA + (ar + i * 16) * 512 + (kbA ^ sw));
#pragma unroll
      for (int j = 0; j < 4; ++j)
        bfr[j] = *(const short8*)(bT + (bn + j * 16) * 128 + (kbB ^ sw));
#pragma unroll
      for (int i = 0; i < 4; ++i)
#pragma unroll
        for (int j = 0; j < 4; ++j)
          acc[i][j] = __builtin_amdgcn_mfma_f32_16x16x32_bf16(af[i], bfr[j], acc[i][j], 0, 0, 0);
    }
  }
  __syncthreads();
}

template<bool RESID>
__device__ __forceinline__ void dev_act_to_hA(f32x4 acc[4][4], char* hA, const float* sS,
                                              int base, int t)
{
  const int l = t & 63, wv = t >> 6, wr = wv >> 2, wc = wv & 3;
  const int r0 = wr * 64 + ((l >> 4) << 2);
#pragma unroll
  for (int j = 0; j < 4; ++j) {
    const int col = wc * 64 + (l & 15) + j * 16;
    const float a = sS[base + col], cb = sS[base + 512 + col];
#pragma unroll
    for (int i = 0; i < 4; ++i) {
#pragma unroll
      for (int q = 0; q < 4; ++q) {
        const int row = r0 + i * 16 + q;
        char* p = hA + row * 512 + (((col * 2)) ^ ((row & 7) << 4));
        float v = relu_(fmaf(acc[i][j][q], a, cb));
        if (RESID) v += bfs(*(const short*)p);
        *(unsigned short*)p = bf16b(v);
      }
    }
  }
}

__device__ __forceinline__ void dev_dot_emit(f32x4 acc[4][4], const char* hA, const float* sS,
                                             float* __restrict__ out, int m0, int E, int t)
{
  const int l = t & 63, wv = t >> 6, wr = wv >> 2, wc = wv & 3;
  const int r0 = wr * 64 + ((l >> 4) << 2);
  float part[4][4];
#pragma unroll
  for (int i = 0; i < 4; ++i)
#pragma unroll
    for (int q = 0; q < 4; ++q) part[i][q] = 0.f;
#pragma unroll
  for (int j = 0; j < 4; ++j) {
    const int col = wc * 64 + (l & 15) + j * 16;
    const float a2 = sS[1536 + col], cb2 = sS[2048 + col], wfv = sS[2304 + col];
#pragma unroll
    for (int i = 0; i < 4; ++i) {
#pragma unroll
      for (int q = 0; q < 4; ++q) {
        const int row = r0 + i * 16 + q;
        const float o1 = bfs(*(const short*)(hA + row * 512 + (((col * 2)) ^ ((row & 7) << 4))));
        const float v = relu_(fmaf(acc[i][j][q], a2, cb2)) + o1;
        part[i][q] = fmaf(v, wfv, part[i][q]);
      }
    }
  }
#pragma unroll
  for (int i = 0; i < 4; ++i)
#pragma unroll
    for (int q = 0; q < 4; ++q) {
      float p = part[i][q];
      p += __shfl_xor(p, 1); p += __shfl_xor(p, 2); p += __shfl_xor(p, 4); p += __shfl_xor(p, 8);
      if ((l & 15) == 0) {
        const int row = m0 + r0 + i * 16 + q;
        if (row < E) atomicAdd(&out[row], p);
      }
    }
}

// KIND 0: G4 -> stats4 | KIND 2: ->G1 stats1 | KIND 3: ->G2 stats2 | KIND 4: ->G2 dot->out
template<int KIND>
__global__ __launch_bounds__(512) void k_chain(
    const float* __restrict__ x, const int* __restrict__ ei, const int* __restrict__ flagp,
    const unsigned short* __restrict__ wt4, const unsigned short* __restrict__ wt1,
    const unsigned short* __restrict__ wt2,
    const float* __restrict__ b4, const float* __restrict__ b1, const float* __restrict__ b2,
    const float* __restrict__ scale, const float* __restrict__ wf,
    float* __restrict__ stats, float* __restrict__ out, int E)
{
  __shared__ __align__(16) char hA[65536];
  __shared__ __align__(16) char bT[32768];
  __shared__ float sS[2560];

  const int t = threadIdx.x;
  const int m0 = blockIdx.x * 128;

  if (KIND != 0) {
    for (int i = t; i < 2560; i += 512) sS[i] = (i < 2304) ? scale[i] : wf[i - 2304];
  }

  int e = m0 + (t & 127); if (e >= E) e = E - 1;
  int sN, dN;
  if (flagp[0]) { sN = ei[2 * e]; dN = ei[2 * (E + e)]; }
  else          { sN = ei[e];     dN = ei[E + e]; }

  dev_stage_gather(hA, x, sN, dN, t);

  f32x4 acc[4][4];
  dev_gemm_hA(acc, hA, bT, wt4, t);
  if (KIND == 0) { dev_epilogue_stats(acc, b4, stats, m0, E, t); return; }

  dev_act_to_hA<false>(acc, hA, sS, 0, t);
  dev_gemm_hA(acc, hA, bT, wt1, t);
  if (KIND == 2) { dev_epilogue_stats(acc, b1, stats, m0, E, t); return; }
  dev_act_to_hA<true>(acc, hA, sS, 768, t);
  dev_gemm_hA(acc, hA, bT, wt2, t);
  if (KIND == 3) { dev_epilogue_stats(acc, b2, stats, m0, E, t); return; }
  dev_dot_emit(acc, hA, sS, out, m0, E, t);
}

extern "C" void kernel_launch(void* const* d_in, const int* in_sizes, int n_in,
                              void* d_out, int out_size, void* d_ws, size_t ws_size,
                              hipStream_t stream) {
  const float* x   = (const float*)d_in[0];
  const int*   ei  = (const int*)d_in[1];
  const float* W4  = (const float*)d_in[2];
  const float* b4  = (const float*)d_in[3];
  const float* g4  = (const float*)d_in[4];
  const float* be4 = (const float*)d_in[5];
  const float* W1  = (const float*)d_in[6];
  const float* b1  = (const float*)d_in[7];
  const float* g1  = (const float*)d_in[8];
  const float* be1 = (const float*)d_in[9];
  const float* W2  = (const float*)d_in[10];
  const float* b2  = (const float*)d_in[11];
  const float* g2  = (const float*)d_in[12];
  const float* be2 = (const float*)d_in[13];
  const float* Wf  = (const float*)d_in[14];
  const float* bfp = (const float*)d_in[15];
  float* out = (float*)d_out;

  const int E = out_size;
  const int MTg = (E + 127) / 128;
  const float invE = 1.0f / (float)E;

  char* ws = (char*)d_ws;
  unsigned short* wt4 = (unsigned short*)(ws);
  unsigned short* wt1 = (unsigned short*)(ws + 131072);
  unsigned short* wt2 = (unsigned short*)(ws + 262144);
  float* stats = (float*)(ws + 393216);   // 3 x (sum[256], sumsq[256])
  float* scale = (float*)(ws + 399360);   // 3 x (a, c_std, c_b)[256]
  int*   flag  = (int*)(ws + 408576);
  const size_t fixed = 409600;
  const size_t ypad = (size_t)MTg * 65536;
  unsigned short* buf = (unsigned short*)(ws + fixed);

  if (ws_size < fixed) {
    k_zero<<<(E + 255) / 256, 256, 0, stream>>>(out, bfp, E);
    return;
  }

  k_init<<<1, 256, 0, stream>>>(ei, stats, flag);
  k_prep<<<192, 256, 0, stream>>>(W4, W1, W2, wt4, wt1, wt2);
  k_zero<<<(E + 255) / 256, 256, 0, stream>>>(out, bfp, E);

  if (ws_size >= fixed + ypad) {
    // P1: gather -> G4 -> stats4
    k_gemm2<0, 0><<<MTg, 512, 0, stream>>>((const void*)x, ei, flag, wt4, b4,
                                           nullptr, nullptr, nullptr, stats, nullptr, E);
    k_stats<<<1, 256, 0, stream>>>(stats, g4, be4, b4, scale, invE);
    // P3: gather -> G4 -> h = act4 -> buf
    k_gemm2<0, 1><<<MTg, 512, 0, stream>>>((const void*)x, ei, flag, wt4, nullptr,
                                           scale, nullptr, buf, nullptr, nullptr, E);
    // P4: h -> G1 -> stats1
    k_gemm2<1, 0><<<MTg, 512, 0, stream>>>((const void*)buf, nullptr, flag, wt1, b1,
                                           nullptr, nullptr, nullptr, stats + 512, nullptr, E);
    k_stats<<<1, 256, 0, stream>>>(stats + 512, g1, be1, b1, scale + 768, invE);
    // P6: h -> G1 -> out1 = act1 + h -> buf (in place) + dot(out1,wf) -> out
    k_gemm2<1, 2><<<MTg, 512, 0, stream>>>((const void*)buf, nullptr, flag, wt1, nullptr,
                                           scale + 768, Wf, buf, nullptr, out, E);
    // P7: out1 -> G2 -> stats2
    k_gemm2<1, 0><<<MTg, 512, 0, stream>>>((const void*)buf, nullptr, flag, wt2, b2,
                                           nullptr, nullptr, nullptr, stats + 1024, nullptr, E);
    k_stats<<<1, 256, 0, stream>>>(stats + 1024, g2, be2, b2, scale + 1536, invE);
    // P9: out1 -> G2 -> dot(act2,wf) -> out
    k_gemm2<1, 3><<<MTg, 512, 0, stream>>>((const void*)buf, nullptr, flag, wt2, nullptr,
                                           scale + 1536, Wf, nullptr, nullptr, out, E);
  } else {
    k_chain<0><<<MTg, 512, 0, stream>>>(x, ei, flag, wt4, wt1, wt2, b4, b1, b2,
                                        scale, Wf, stats, out, E);
    k_stats<<<1, 256, 0, stream>>>(stats, g4, be4, b4, scale, invE);
    k_chain<2><<<MTg, 512, 0, stream>>>(x, ei, flag, wt4, wt1, wt2, b4, b1, b2,
                                        scale, Wf, stats + 512, out, E);
    k_stats<<<1, 256, 0, stream>>>(stats + 512, g1, be1, b1, scale + 768, invE);
    k_chain<3><<<MTg, 512, 0, stream>>>(x, ei, flag, wt4, wt1, wt2, b4, b1, b2,
                                        scale, Wf, stats + 1024, out, E);
    k_stats<<<1, 256, 0, stream>>>(stats + 1024, g2, be2, b2, scale + 1536, invE);
    k_chain<4><<<MTg, 512, 0, stream>>>(x, ei, flag, wt4, wt1, wt2, b4, b1, b2,
                                        scale, Wf, nullptr, out, E);
  }
}